// Round 8
// baseline (113.828 us; speedup 1.0000x reference)
//
#include <hip/hip_runtime.h>

// BaseModel_3100966387783 — per-variable masked 3-layer MLP, b=8192, D=128, h=64, o=2.
//
// R8: wave-PAIR weight split for 4 waves/SIMD occupancy.
//   - block = 256 thr = 4 waves = 2 pairs; a pair processes one 16-row batch
//     tile per iter (8 iters). Wave `half` of a pair holds w0/w1 rows for
//     i ∈ [half*32, half*32+32) only -> 56 weight regs instead of 104.
//   - x tiles: global_load_lds DMA into double-buffered LDS (+2-iter lookahead,
//     covered by the single per-iter barrier). Zero VGPR cost.
//   - L0: 8 MFMA/wave (its 2 "it" tiles x 4 ks), epi0 -> h brick (half writes
//     brick ks=half exactly — i=it*16+... maps ks_w = half). Double-buffered.
//   - L1: 4 MFMA/wave (2 i2t x 2 ks) reading both h bricks after the barrier.
//   - L2: VALU dot over the wave's 32 i2 + quad shfl; cross-half combine via
//     LDS, deferred one iteration so the same barrier orders it.
//   - ONE __syncthreads per iter. ~105 VGPR + 8 AGPR -> 4 waves/SIMD.
// brick = 1 KB = 64 lanes x 16 B bf16; lane l holds
//   T[tile*16 + (l&15)][ks*32 + (l>>4)*8 + 0..7]  (one MFMA A/B fragment).

typedef __bf16 bf16_t;
typedef __bf16 bf16x8 __attribute__((ext_vector_type(8)));
typedef float  f32x4  __attribute__((ext_vector_type(4)));
typedef __fp16 f16x2  __attribute__((ext_vector_type(2)));

#define LEAKY 0.01f

// ---------------- ws brick regions (byte offsets) ----------------
#define XB_OFF   0u                  // x bricks:   512 row-tiles x 4 ks = 2048 bricks
#define W0B_OFF  (2048u*1024u)       // w0 masked: 128 t x 4 it x 4 ks = 2048
#define W1B_OFF  (4096u*1024u)       // w1:        128 t x 4 it x 2 ks = 1024
// total ws need: 5120 KiB

__device__ __forceinline__ void async_copy16(void* lds, const void* g) {
    __builtin_amdgcn_global_load_lds(
        (const __attribute__((address_space(1))) unsigned int*)g,
        (__attribute__((address_space(3))) unsigned int*)lds, 16, 0, 0);
}

// =================== pre-kernel: fp32 -> bf16 brick-ify ===================
__global__ __launch_bounds__(256)
void brickify(const float* __restrict__ x,  const float* __restrict__ w0,
              const float* __restrict__ w1, unsigned char* __restrict__ ws)
{
    const int wid  = blockIdx.x * 4 + (threadIdx.x >> 6);  // one wave = one brick
    const int lane = threadIdx.x & 63;
    const int lr = lane & 15, lq = lane >> 4;

    float v[8];
    if (wid < 2048) {                        // ---- x bricks ----
        int bt = wid >> 5, rem = wid & 31, nt = rem >> 2, ks = rem & 3;
        const float* s = x + (size_t)(bt*128 + nt*16 + lr) * 128 + ks*32 + lq*8;
        const float4 a = *(const float4*)s, b = *(const float4*)(s + 4);
        v[0]=a.x; v[1]=a.y; v[2]=a.z; v[3]=a.w;
        v[4]=b.x; v[5]=b.y; v[6]=b.z; v[7]=b.w;
    } else if (wid < 4096) {                 // ---- w0 bricks (masked j==t -> 0) ----
        int u = wid - 2048, t = u >> 4, rem = u & 15, it = rem >> 2, ks = rem & 3;
        int k0 = ks*32 + lq*8;
        const float* s = w0 + (size_t)(t*64 + it*16 + lr) * 128 + k0;
        const float4 a = *(const float4*)s, b = *(const float4*)(s + 4);
        v[0]=a.x; v[1]=a.y; v[2]=a.z; v[3]=a.w;
        v[4]=b.x; v[5]=b.y; v[6]=b.z; v[7]=b.w;
        #pragma unroll
        for (int j = 0; j < 8; ++j) if (k0 + j == t) v[j] = 0.f;
    } else {                                 // ---- w1 bricks ----
        int u = wid - 4096, t = u >> 3, rem = u & 7, it = rem >> 1, ks = rem & 1;
        const float* s = w1 + (size_t)(t*64 + it*16 + lr) * 64 + ks*32 + lq*8;
        const float4 a = *(const float4*)s, b = *(const float4*)(s + 4);
        v[0]=a.x; v[1]=a.y; v[2]=a.z; v[3]=a.w;
        v[4]=b.x; v[5]=b.y; v[6]=b.z; v[7]=b.w;
    }
    union { bf16_t h[8]; uint4 q; } pk;
    #pragma unroll
    for (int j = 0; j < 8; ++j) pk.h[j] = (bf16_t)v[j];
    ((uint4*)ws)[(size_t)wid * 64 + lane] = pk.q;   // dst = brick*1024 + lane*16
}

// =========================== main fused kernel ===========================
__global__ __launch_bounds__(256, 4)
void fused_mlp(const unsigned char* __restrict__ ws,
               const float* __restrict__ w2,
               const float* __restrict__ b0, const float* __restrict__ b1,
               const float* __restrict__ b2, float* __restrict__ out)
{
    __shared__ __align__(1024) unsigned char xsm[16384];  // [pair][buf][4 KB]
    __shared__ __align__(1024) unsigned char hsm[8192];   // [pair][buf][2 KB]
    __shared__ __align__(16)   float psm[2][2][2][16][2]; // [buf][pair][half][lr][o]

    const int tid  = threadIdx.x;
    const int wv   = tid >> 6;
    const int pair = wv >> 1;          // 0,1
    const int half = wv & 1;           // which weight half this wave owns
    const int lane = tid & 63;
    const int lr = lane & 15, lq = lane >> 4;
    const int g  = blockIdx.x;         // 0..31; block covers tiles g*16 .. g*16+15
    const int t  = blockIdx.y;

    // ---- weight halves: global -> registers ----
    const unsigned char* w0p = ws + W0B_OFF + (size_t)t*16384 + lane*16;
    const unsigned char* w1p = ws + W1B_OFF + (size_t)t*8192  + lane*16;
    bf16x8 w0f[2][4], w1f[2][2];
    #pragma unroll
    for (int itl = 0; itl < 2; ++itl) {
        const int it = half*2 + itl;
        #pragma unroll
        for (int ks = 0; ks < 4; ++ks)
            w0f[itl][ks] = *(const bf16x8*)(w0p + (it*4+ks)*1024);
        #pragma unroll
        for (int ks = 0; ks < 2; ++ks)
            w1f[itl][ks] = *(const bf16x8*)(w1p + (it*2+ks)*1024);
    }
    // ---- w2 half as f16 pairs in C-layout ----
    f16x2 w2h[2][2][2];
    #pragma unroll
    for (int o = 0; o < 2; ++o)
        #pragma unroll
        for (int itl = 0; itl < 2; ++itl) {
            f32x4 v = *(const f32x4*)(w2 + t*128 + o*64 + (half*2+itl)*16 + lq*4);
            w2h[o][itl][0] = __builtin_amdgcn_cvt_pkrtz(v[0], v[1]);
            w2h[o][itl][1] = __builtin_amdgcn_cvt_pkrtz(v[2], v[3]);
        }
    // ---- bias halves ----
    f32x4 b0q[2], b1q[2];
    #pragma unroll
    for (int itl = 0; itl < 2; ++itl) {
        b0q[itl] = *(const f32x4*)(b0 + t*64 + (half*2+itl)*16 + lq*4);
        b1q[itl] = *(const f32x4*)(b1 + t*64 + (half*2+itl)*16 + lq*4);
    }
    const float2 b2v = *(const float2*)(b2 + t*2);

    const unsigned char* xsrc0 = ws + XB_OFF + (size_t)(g*16 + pair)*4096 + lane*16;
    unsigned char* xd0 = xsm + pair*8192;
    const int wboff = ((lq >> 1) * 16 + lr) * 16 + (lq & 1) * 8;

    // ---- prologue: DMA x tiles s=0,1 into the two buffers ----
    if (half == 0) {
        #pragma unroll
        for (int c = 0; c < 4; ++c)
            async_copy16(xd0 + c*1024, xsrc0 + c*1024);
        #pragma unroll
        for (int c = 0; c < 4; ++c)
            async_copy16(xd0 + 4096 + c*1024, xsrc0 + 2*4096 + c*1024);
    }
    __syncthreads();

    for (int s = 0; s < 8; ++s) {
        // ======== layer 0, tile(s): 8 MFMA over this wave's 2 "it" tiles ========
        const unsigned char* xb = xsm + pair*8192 + (s&1)*4096 + lane*16;
        f32x4 acc[2];
        acc[0] = b0q[0]; acc[1] = b0q[1];
        #pragma unroll
        for (int ks = 0; ks < 4; ++ks) {
            bf16x8 xk = *(const bf16x8*)(xb + ks*1024);
            acc[0] = __builtin_amdgcn_mfma_f32_16x16x32_bf16(w0f[0][ks], xk, acc[0], 0, 0, 0);
            acc[1] = __builtin_amdgcn_mfma_f32_16x16x32_bf16(w0f[1][ks], xk, acc[1], 0, 0, 0);
        }

        // ======== epi0 -> h brick ks=half (i = (half*2+itl)*16+... => brick half) ====
        unsigned char* hb = hsm + pair*4096 + (s&1)*2048;
        #pragma unroll
        for (int itl = 0; itl < 2; ++itl) {
            union { bf16_t h[4]; unsigned long long u; } pk;
            #pragma unroll
            for (int r = 0; r < 4; ++r) {
                float u = acc[itl][r];
                pk.h[r] = (bf16_t)fmaxf(u, LEAKY * u);
            }
            *(unsigned long long*)(hb + half*1024 + itl*512 + wboff) = pk.u;
        }

        __syncthreads();   // the ONE barrier: h(s) ready, x DMA(s+1) drained,
                           // partials(s-1) visible

        // ======== deferred combine + store for tile (s-1) ========
        if (s > 0 && half == 0 && lq == 0) {
            const int pb = (s-1) & 1;
            float2 pa = *(const float2*)&psm[pb][pair][0][lr][0];
            float2 pc = *(const float2*)&psm[pb][pair][1][lr][0];
            int row = (g*16 + (s-1)*2 + pair)*16 + lr;
            float2 o2 = { pa.x + pc.x + b2v.x, pa.y + pc.y + b2v.y };
            *(float2*)(out + (size_t)row*256 + t*2) = o2;
        }

        // ======== DMA x tile (s+2) into the just-freed buffer ========
        if (half == 0 && s + 2 < 8) {
            const unsigned char* xs = xsrc0 + (size_t)(s+2)*2*4096;
            unsigned char* xd = xd0 + (s&1)*4096;
            #pragma unroll
            for (int c = 0; c < 4; ++c)
                async_copy16(xd + c*1024, xs + c*1024);
        }

        // ======== layer 1: 4 MFMA, full K from both h bricks ========
        bf16x8 hf0 = *(const bf16x8*)(hb + lane*16);
        bf16x8 hf1 = *(const bf16x8*)(hb + 1024 + lane*16);
        acc[0] = b1q[0]; acc[1] = b1q[1];
        #pragma unroll
        for (int itl = 0; itl < 2; ++itl) {
            acc[itl] = __builtin_amdgcn_mfma_f32_16x16x32_bf16(w1f[itl][0], hf0, acc[itl], 0, 0, 0);
            acc[itl] = __builtin_amdgcn_mfma_f32_16x16x32_bf16(w1f[itl][1], hf1, acc[itl], 0, 0, 0);
        }

        // ======== layer 2 partial: dot over this wave's 32 i2 + quad reduce ======
        float p0 = 0.f, p1 = 0.f;
        #pragma unroll
        for (int itl = 0; itl < 2; ++itl) {
            #pragma unroll
            for (int p = 0; p < 2; ++p) {
                float u0 = acc[itl][2*p],   v0 = fmaxf(u0, LEAKY * u0);
                float u1 = acc[itl][2*p+1], v1 = fmaxf(u1, LEAKY * u1);
                f16x2 hh = __builtin_amdgcn_cvt_pkrtz(v0, v1);
                p0 = __builtin_amdgcn_fdot2(w2h[0][itl][p], hh, p0, false);
                p1 = __builtin_amdgcn_fdot2(w2h[1][itl][p], hh, p1, false);
            }
        }
        p0 += __shfl_xor(p0, 16); p0 += __shfl_xor(p0, 32);
        p1 += __shfl_xor(p1, 16); p1 += __shfl_xor(p1, 32);
        if (lq == 0) {
            float2 pv = { p0, p1 };
            *(float2*)&psm[s&1][pair][half][lr][0] = pv;
        }
    }

    // ======== tail: combine + store tile (7) ========
    __syncthreads();
    if (half == 0 && lq == 0) {
        float2 pa = *(const float2*)&psm[1][pair][0][lr][0];
        float2 pc = *(const float2*)&psm[1][pair][1][lr][0];
        int row = (g*16 + 7*2 + pair)*16 + lr;
        float2 o2 = { pa.x + pc.x + b2v.x, pa.y + pc.y + b2v.y };
        *(float2*)(out + (size_t)row*256 + t*2) = o2;
    }
}

extern "C" void kernel_launch(void* const* d_in, const int* in_sizes, int n_in,
                              void* d_out, int out_size, void* d_ws, size_t ws_size,
                              hipStream_t stream) {
    const float* x  = (const float*)d_in[0];
    const float* w0 = (const float*)d_in[1];
    const float* w1 = (const float*)d_in[2];
    const float* w2 = (const float*)d_in[3];
    const float* b0 = (const float*)d_in[4];
    const float* b1 = (const float*)d_in[5];
    const float* b2 = (const float*)d_in[6];
    unsigned char* ws = (unsigned char*)d_ws;   // needs 5120 KiB
    float* out = (float*)d_out;

    brickify<<<dim3(1280), dim3(256), 0, stream>>>(x, w0, w1, ws);
    // grid (32 row-groups x 128 t) = 4096 blocks; 4 waves = 2 pairs each;
    // each pair: 8 iters x 16-row tiles -> 256 rows/block.
    fused_mlp<<<dim3(32, 128), dim3(256), 0, stream>>>(ws, w2, b0, b1, b2, out);
}